// Round 1
// baseline (356.486 us; speedup 1.0000x reference)
//
#include <hip/hip_runtime.h>

// ---------------------------------------------------------------------------
// MSCrossAttnBlock on MI355X (gfx950).
// B=4, E=32, LQ=1024, D=1024, NH=16, DH=64, NP=4. All levels are 32x32.
// R5: GEMM K-loop rewritten as 2-phase double-buffered LDS pipeline with
//     direct global_load_lds_dwordx4 staging (T3-lite). One barrier per
//     64-K step; stage latency hidden under MFMA phase. LDS swizzle is
//     unchanged (slot == lane -> matches global_load_lds base+lane*16).
//     9 dispatches.
// ---------------------------------------------------------------------------

#define DEV __device__ __forceinline__

typedef float f32x4 __attribute__((ext_vector_type(4)));
typedef __bf16 bf16x8 __attribute__((ext_vector_type(8)));

DEV unsigned short f2bf(float f) {
  union { float f; unsigned u; } a; a.f = f;
  unsigned r = a.u + 0x7fffu + ((a.u >> 16) & 1u);
  return (unsigned short)(r >> 16);
}
DEV float bf2f(unsigned short h) {
  union { unsigned u; float f; } a; a.u = ((unsigned)h) << 16;
  return a.f;
}

// async global -> LDS, 16B per lane; LDS dest = uniform base + lane*16.
DEV void gl_lds16(const unsigned short* g, unsigned short* l) {
  __builtin_amdgcn_global_load_lds(
      (const __attribute__((address_space(1))) void*)g,
      (__attribute__((address_space(3))) void*)l, 16, 0, 0);
}

// ---------------- merged weight fp32 -> bf16 conversion --------------------
struct CvtArgs {
  const float* src[8];
  unsigned short* dst;
  int off4[9];  // prefix sums, float4 units
};

__global__ __launch_bounds__(256) void f2bf_multi(CvtArgs a) {
  int i = blockIdx.x * 256 + threadIdx.x;  // float4 index, exact grid
  int seg = 0;
  #pragma unroll
  for (int s = 1; s < 8; ++s) seg += (i >= a.off4[s]) ? 1 : 0;
  const float4 v = ((const float4*)a.src[seg])[i - a.off4[seg]];
  unsigned short* o = a.dst + (size_t)i * 4;
  o[0] = f2bf(v.x); o[1] = f2bf(v.y); o[2] = f2bf(v.z); o[3] = f2bf(v.w);
}

// ---------------- LayerNorm: one WAVE per row (no barriers, no LDS) --------
DEV void ln_row_wave(const float* __restrict__ xr, const float* __restrict__ g,
                     const float* __restrict__ b,
                     unsigned short* __restrict__ op_row) {
  const int lane = threadIdx.x & 63;
  float4 v[4];
  float s = 0.f, s2 = 0.f;
  #pragma unroll
  for (int j = 0; j < 4; ++j) {
    v[j] = ((const float4*)xr)[lane + 64 * j];
    s  += v[j].x + v[j].y + v[j].z + v[j].w;
    s2 += v[j].x*v[j].x + v[j].y*v[j].y + v[j].z*v[j].z + v[j].w*v[j].w;
  }
  #pragma unroll
  for (int o = 32; o; o >>= 1) { s += __shfl_xor(s, o); s2 += __shfl_xor(s2, o); }
  const float mean = s * (1.f / 1024.f);
  const float rstd = rsqrtf(s2 * (1.f / 1024.f) - mean * mean + 1e-6f);
  #pragma unroll
  for (int j = 0; j < 4; ++j) {
    float4 gg = ((const float4*)g)[lane + 64 * j];
    float4 bb = ((const float4*)b)[lane + 64 * j];
    ushort4 r;
    r.x = f2bf((v[j].x - mean) * rstd * gg.x + bb.x);
    r.y = f2bf((v[j].y - mean) * rstd * gg.y + bb.y);
    r.z = f2bf((v[j].z - mean) * rstd * gg.z + bb.z);
    r.w = f2bf((v[j].w - mean) * rstd * gg.w + bb.w);
    ((ushort4*)op_row)[lane + 64 * j] = r;
  }
}

__global__ __launch_bounds__(256) void ln_wave_kernel(
    const float* __restrict__ x, const float* __restrict__ g,
    const float* __restrict__ b, unsigned short* __restrict__ out) {
  int row = blockIdx.x * 4 + (threadIdx.x >> 6);
  ln_row_wave(x + (size_t)row * 1024, g, b, out + (size_t)row * 1024);
}

// rows 0..16383: feat levels -> f_ln (B,4,1024,1024); rows 16384..20479: q_ln.
__global__ __launch_bounds__(256) void ln5_wave_kernel(
    const float* __restrict__ s0, const float* __restrict__ s1,
    const float* __restrict__ s2, const float* __restrict__ s3,
    const float* __restrict__ fg, const float* __restrict__ fb,
    const float* __restrict__ qg, const float* __restrict__ qb,
    unsigned short* __restrict__ f_out, unsigned short* __restrict__ q_out) {
  int row = blockIdx.x * 4 + (threadIdx.x >> 6);  // 0..20479
  if (row < 16384) {
    int l = row >> 12, inner = row & 4095;
    const float* srcs[4] = {s0, s1, s2, s3};
    int orow = (inner >> 10) * 4096 + l * 1024 + (inner & 1023);
    ln_row_wave(srcs[l] + (size_t)inner * 1024, fg, fb,
                f_out + (size_t)orow * 1024);
  } else {
    int inner = row - 16384;
    ln_row_wave(s3 + (size_t)inner * 1024, qg, qb,
                q_out + (size_t)inner * 1024);
  }
}

// ---------------- bf16 MFMA GEMM, gload_lds + dbuf LDS, swizzled -----------
// C[M,N] = A[M,K] @ W[N,K]^T (+bias). BK=64 as two 32-k sub-tiles.
// 2-phase pipeline: stage(t+1) issued before compute(t); __syncthreads'
// vmcnt(0) drain lands after the MFMA phase, hiding the staging latency.
// LDS layout conflict-free (R2/R3: SQ_LDS_BANK_CONFLICT = 0); lane l of the
// staging wave writes granule slot l -> matches global_load_lds semantics.
// EPI: 0=f32, 1=bf16, 2=CA split(off512|attw256), 3=SA split(val1024 bf16|
//      off128 f32|attw64 f32), 4=final combine -> d_out.
struct GemmP {
  const unsigned short* A; const unsigned short* W;
  void* C; void* C1; void* C2;
  const float* b0; const float* b1; const float* b2;
  const float* src3; const float* g1; const float* g2; const float* attnp;
  int M, N, K, tilesM;
};

template <int BM, int BN, int EPI>
DEV void gemm_body(const GemmP& P, int id, unsigned short* smem) {
  constexpr int WMT = BM / 2, WNT = BN / 2;
  constexpr int MF = WMT / 16, NF = WNT / 16;
  constexpr int PA = BM / 64, PB = BN / 64;    // granule passes per sub-tile
  constexpr int BUF = (BM + BN) * 64;          // elements per LDS buffer
  const int tid = threadIdx.x;
  const int wave = tid >> 6, lane = tid & 63;
  const int wm = (wave & 1) * WMT, wn = (wave >> 1) * WNT;
  const int m0 = (id % P.tilesM) * BM;
  const int n0 = (id / P.tilesM) * BN;
  const int lq = lane >> 4, lm = lane & 15;
  const int r16 = lane >> 2;                    // row within granule
  const int cst = lane & 3;                     // slot within row
  const int csrc = cst ^ ((r16 >> 1) & 3);      // global k-chunk for slot
  const int aslot = lq ^ ((lm >> 1) & 3);       // read slot for chunk lq

  f32x4 acc[MF][NF] = {};
  const int kTiles = P.K >> 6;

  // per-lane global base pointers (swizzled source, rule: src swz == read swz)
  const unsigned short* gA[PA];
  #pragma unroll
  for (int p = 0; p < PA; ++p) {
    int grow = m0 + (wave + 4 * p) * 16 + r16;
    gA[p] = P.A + (size_t)grow * P.K + csrc * 8;
  }
  const unsigned short* gB[PB];
  #pragma unroll
  for (int p = 0; p < PB; ++p) {
    int grow = min(n0 + (wave + 4 * p) * 16 + r16, P.N - 1);
    gB[p] = P.W + (size_t)grow * P.K + csrc * 8;
  }

  auto stage = [&](int b, int t) {
    unsigned short* bA = smem + b * BUF;
    unsigned short* bB = bA + BM * 64;
    const int k0 = t << 6;
    #pragma unroll
    for (int s = 0; s < 2; ++s) {
      #pragma unroll
      for (int p = 0; p < PA; ++p)
        gl_lds16(gA[p] + k0 + s * 32,
                 bA + s * BM * 32 + (wave + 4 * p) * 512);
      #pragma unroll
      for (int p = 0; p < PB; ++p)
        gl_lds16(gB[p] + k0 + s * 32,
                 bB + s * BN * 32 + (wave + 4 * p) * 512);
    }
  };

  stage(0, 0);
  __syncthreads();                 // vmcnt(0) drain: buf0 ready
  int cur = 0;
  #pragma unroll 1
  for (int t = 0; t < kTiles; ++t) {
    if (t + 1 < kTiles) stage(cur ^ 1, t + 1);  // async issue, no wait yet
    const unsigned short* bA = smem + cur * BUF;
    const unsigned short* bB = bA + BM * 64;
    #pragma unroll
    for (int s = 0; s < 2; ++s) {
      bf16x8 af[MF], bfr[NF];
      #pragma unroll
      for (int mi = 0; mi < MF; ++mi)
        af[mi] = *(const bf16x8*)(bA + s * BM * 32 + ((wm >> 4) + mi) * 512 + lm * 32 + aslot * 8);
      #pragma unroll
      for (int ni = 0; ni < NF; ++ni)
        bfr[ni] = *(const bf16x8*)(bB + s * BN * 32 + ((wn >> 4) + ni) * 512 + lm * 32 + aslot * 8);
      #pragma unroll
      for (int mi = 0; mi < MF; ++mi)
        #pragma unroll
        for (int ni = 0; ni < NF; ++ni)
          acc[mi][ni] = __builtin_amdgcn_mfma_f32_16x16x32_bf16(
              af[mi], bfr[ni], acc[mi][ni], 0, 0, 0);
    }
    __syncthreads();   // drains this iter's stage (after MFMA) + barrier
    cur ^= 1;
  }

  #pragma unroll
  for (int mi = 0; mi < MF; ++mi) {
    #pragma unroll
    for (int ni = 0; ni < NF; ++ni) {
      const int col = n0 + wn + ni * 16 + lm;
      #pragma unroll
      for (int r2 = 0; r2 < 4; ++r2) {
        const int row = m0 + wm + mi * 16 + lq * 4 + r2;
        float v = acc[mi][ni][r2];
        if constexpr (EPI == 0) {
          ((float*)P.C)[(size_t)row * 1024 + col] = v + P.b0[col];
        } else if constexpr (EPI == 1) {
          ((unsigned short*)P.C)[(size_t)row * 1024 + col] = f2bf(v + P.b0[col]);
        } else if constexpr (EPI == 2) {
          if (col < 512)
            ((float*)P.C)[(size_t)row * 512 + col] = v + P.b0[col];
          else
            ((float*)P.C1)[(size_t)row * 256 + col - 512] = v + P.b1[col - 512];
        } else if constexpr (EPI == 3) {
          if (col < 1024)
            ((unsigned short*)P.C)[(size_t)row * 1024 + col] = f2bf(v + P.b0[col]);
          else if (col < 1152)
            ((float*)P.C1)[(size_t)row * 128 + col - 1024] = v + P.b1[col - 1024];
          else if (col < 1216)
            ((float*)P.C2)[(size_t)row * 64 + col - 1152] = v + P.b2[col - 1152];
        } else {  // EPI == 4: out = src3 + g1*(attn + g2*(v+b))
          size_t i = (size_t)row * 1024 + col;
          float vv = v + P.b0[col];
          ((float*)P.C)[i] = P.src3[i] + P.g1[col] * (P.attnp[i] + P.g2[col] * vv);
        }
      }
    }
  }
}

template <int BM, int BN, int EPI>
__global__ __launch_bounds__(256) void gemm_v3(GemmP P) {
  extern __shared__ __align__(16) unsigned short smem[];
  gemm_body<BM, BN, EPI>(P, blockIdx.x, smem);
}

// merged CA dispatch: blocks [0,split) = val GEMM (EPI1), rest = off/attw (EPI2)
template <int BM, int BN>
__global__ __launch_bounds__(256) void gemm_dual(GemmP Pv, GemmP Po, int split) {
  extern __shared__ __align__(16) unsigned short smem[];
  if ((int)blockIdx.x < split)
    gemm_body<BM, BN, 1>(Pv, blockIdx.x, smem);
  else
    gemm_body<BM, BN, 2>(Po, blockIdx.x - split, smem);
}

// ---------------- fused softmax + MS-deform bilinear sampling --------------
template <int NLEV>
__global__ __launch_bounds__(256) void ms_sample_fused(
    const unsigned short* __restrict__ value, const float* __restrict__ off,
    const float* __restrict__ logits, unsigned short* __restrict__ out) {
  const int nq = blockIdx.x;               // n*1024 + q
  const int wave = threadIdx.x >> 6, lane = threadIdx.x & 63;
  const int h = (wave << 2) + (lane >> 4);
  const int c = (lane & 15) << 2;          // channel base (0..60)
  const int q = nq & 1023, n = nq >> 10;
  const float* offp = off + ((size_t)nq * 16 + h) * (NLEV * 8);
  const float* lgp  = logits + ((size_t)nq * 16 + h) * (NLEV * 4);

  float lg[NLEV * 4];
  #pragma unroll
  for (int i = 0; i < NLEV; ++i) {
    float4 v = ((const float4*)lgp)[i];
    lg[4*i] = v.x; lg[4*i+1] = v.y; lg[4*i+2] = v.z; lg[4*i+3] = v.w;
  }
  float mx = lg[0];
  #pragma unroll
  for (int i = 1; i < NLEV * 4; ++i) mx = fmaxf(mx, lg[i]);
  float ssum = 0.f;
  #pragma unroll
  for (int i = 0; i < NLEV * 4; ++i) { lg[i] = __expf(lg[i] - mx); ssum += lg[i]; }
  const float inv = 1.f / ssum;

  const float fqx = (float)(q & 31), fqy = (float)(q >> 5);
  float a0 = 0.f, a1 = 0.f, a2 = 0.f, a3 = 0.f;

  #pragma unroll
  for (int l = 0; l < NLEV; ++l) {
    const unsigned short* vl =
        value + ((size_t)(n * NLEV + l) << 20) + h * 64 + c;
    #pragma unroll
    for (int p = 0; p < 4; ++p) {
      float2 o2 = ((const float2*)offp)[l * 4 + p];
      float aw = lg[l * 4 + p] * inv;
      float xx = fqx + o2.x, yy = fqy + o2.y;
      float xf = floorf(xx), yf = floorf(yy);
      float fx = xx - xf, fy = yy - yf;
      int ix = (int)xf, iy = (int)yf;
      int ix1 = ix + 1, iy1 = iy + 1;
      float vx0 = ((unsigned)ix  < 32u) ? 1.f : 0.f;
      float vx1 = ((unsigned)ix1 < 32u) ? 1.f : 0.f;
      float vy0 = ((unsigned)iy  < 32u) ? 1.f : 0.f;
      float vy1 = ((unsigned)iy1 < 32u) ? 1.f : 0.f;
      int cx0 = min(max(ix, 0), 31), cx1 = min(max(ix1, 0), 31);
      int cy0 = min(max(iy, 0), 31), cy1 = min(max(iy1, 0), 31);
      float w00 = (1.f - fx) * (1.f - fy) * vx0 * vy0 * aw;
      float w01 = fx * (1.f - fy) * vx1 * vy0 * aw;
      float w10 = (1.f - fx) * fy * vx0 * vy1 * aw;
      float w11 = fx * fy * vx1 * vy1 * aw;
      ushort4 u00 = *(const ushort4*)(vl + ((size_t)(cy0 * 32 + cx0) << 10));
      ushort4 u01 = *(const ushort4*)(vl + ((size_t)(cy0 * 32 + cx1) << 10));
      ushort4 u10 = *(const ushort4*)(vl + ((size_t)(cy1 * 32 + cx0) << 10));
      ushort4 u11 = *(const ushort4*)(vl + ((size_t)(cy1 * 32 + cx1) << 10));
      a0 += w00 * bf2f(u00.x) + w01 * bf2f(u01.x) + w10 * bf2f(u10.x) + w11 * bf2f(u11.x);
      a1 += w00 * bf2f(u00.y) + w01 * bf2f(u01.y) + w10 * bf2f(u10.y) + w11 * bf2f(u11.y);
      a2 += w00 * bf2f(u00.z) + w01 * bf2f(u01.z) + w10 * bf2f(u10.z) + w11 * bf2f(u11.z);
      a3 += w00 * bf2f(u00.w) + w01 * bf2f(u01.w) + w10 * bf2f(u10.w) + w11 * bf2f(u11.w);
    }
  }
  ushort4 r;
  r.x = f2bf(a0); r.y = f2bf(a1); r.z = f2bf(a2); r.w = f2bf(a3);
  *(ushort4*)(out + ((size_t)nq * 16 + h) * 64 + c) = r;
}

// ---------------------------------------------------------------------------
extern "C" void kernel_launch(void* const* d_in, const int* in_sizes, int n_in,
                              void* d_out, int out_size, void* d_ws,
                              size_t ws_size, hipStream_t stream) {
  (void)in_sizes; (void)n_in; (void)out_size; (void)ws_size;
  const float* src[4] = {(const float*)d_in[0], (const float*)d_in[1],
                         (const float*)d_in[2], (const float*)d_in[3]};
  const float* qn_g = (const float*)d_in[4];
  const float* qn_b = (const float*)d_in[5];
  const float* fn_g = (const float*)d_in[6];
  const float* fn_b = (const float*)d_in[7];
  const float* n1_g = (const float*)d_in[8];
  const float* n1_b = (const float*)d_in[9];
  const float* gamma1 = (const float*)d_in[10];
  const float* gamma2 = (const float*)d_in[11];
  const float* ca_vw = (const float*)d_in[12];
  const float* ca_vb = (const float*)d_in[13];
  const float* ca_ow = (const float*)d_in[14];
  const float* ca_ob = (const float*)d_in[15];
  const float* ca_aw = (const float*)d_in[16];
  const float* ca_ab = (const float*)d_in[17];
  const float* ca_pw = (const float*)d_in[18];
  const float* ca_pb = (const float*)d_in[19];
  const float* sa_vw = (const float*)d_in[20];
  const float* sa_vb = (const float*)d_in[21];
  const float* sa_ow = (const float*)d_in[22];
  const float* sa_ob = (const float*)d_in[23];
  const float* sa_aw = (const float*)d_in[24];
  const float* sa_ab = (const float*)d_in[25];
  const float* sa_pw = (const float*)d_in[26];
  const float* sa_pb = (const float*)d_in[27];

  // ---- workspace layout ----
  char* wsp = (char*)d_ws;
  size_t off = 0;
  auto alloc = [&](size_t bytes) {
    char* r = wsp + off;
    off = (off + bytes + 255) & ~(size_t)255;
    return r;
  };
  const size_t MB = 1024 * 1024;
  unsigned short* w_ca_vw = (unsigned short*)alloc(1024 * 1024 * 2);
  unsigned short* w_ca_ow = (unsigned short*)alloc(512 * 1024 * 2);
  unsigned short* w_ca_aw = (unsigned short*)alloc(256 * 1024 * 2);
  unsigned short* w_ca_pw = (unsigned short*)alloc(1024 * 1024 * 2);
  unsigned short* w_sa_vw = (unsigned short*)alloc(1024 * 1024 * 2);
  unsigned short* w_sa_ow = (unsigned short*)alloc(128 * 1024 * 2);
  unsigned short* w_sa_aw = (unsigned short*)alloc(64 * 1024 * 2);
  unsigned short* w_sa_pw = (unsigned short*)alloc(1024 * 1024 * 2);
  (void)w_ca_aw; (void)w_sa_ow; (void)w_sa_aw;
  char* R1 = alloc(32 * MB);  // f_ln bf16 | attn f32 + attn1 bf16 + samp_sa bf16
  char* R2 = alloc(32 * MB);  // val_ca bf16 | val_sa bf16
  char* R3 = alloc(8 * MB);   // q_ln bf16 | samp_ca bf16
  char* R4 = alloc(8 * MB);   // off_ca f32 | off_sa f32 + attw_sa f32
  char* R5 = alloc(4 * MB);   // attw_ca f32 (raw logits; softmax fused)

  unsigned short* f_ln    = (unsigned short*)R1;
  float*          attn    = (float*)R1;
  unsigned short* attn1   = (unsigned short*)(R1 + 16 * MB);
  unsigned short* samp_sa = (unsigned short*)(R1 + 24 * MB);
  unsigned short* val_ca  = (unsigned short*)R2;
  unsigned short* val_sa  = (unsigned short*)R2;
  unsigned short* q_ln    = (unsigned short*)R3;
  unsigned short* samp_ca = (unsigned short*)R3;
  float*          off_ca  = (float*)R4;
  float*          off_sa  = (float*)R4;
  float*          attw_sa = (float*)(R4 + 4 * MB);
  float*          attw_ca = (float*)R5;

  // ---- 1. merged weight conversion ----
  CvtArgs ca;
  ca.src[0] = ca_vw; ca.src[1] = ca_ow; ca.src[2] = ca_aw; ca.src[3] = ca_pw;
  ca.src[4] = sa_vw; ca.src[5] = sa_ow; ca.src[6] = sa_aw; ca.src[7] = sa_pw;
  ca.dst = w_ca_vw;
  const int sizes4[8] = {262144, 131072, 65536, 262144, 262144, 32768, 16384, 262144};
  ca.off4[0] = 0;
  for (int i = 0; i < 8; ++i) ca.off4[i + 1] = ca.off4[i] + sizes4[i];
  f2bf_multi<<<ca.off4[8] / 256, 256, 0, stream>>>(ca);

  // ---- 2. LayerNorms (feat x4 + query; wave per row) ----
  ln5_wave_kernel<<<5120, 256, 0, stream>>>(src[0], src[1], src[2], src[3],
                                            fn_g, fn_b, qn_g, qn_b, f_ln, q_ln);

  auto mkP = [](const unsigned short* A, const unsigned short* W, void* C,
                const float* b0, int M, int N, int K, int tilesM) {
    GemmP p{}; p.A = A; p.W = W; p.C = C; p.b0 = b0;
    p.M = M; p.N = N; p.K = K; p.tilesM = tilesM;
    return p;
  };

  // dynamic LDS: 2 buffers x (BM+BN)*64 bf16
  constexpr int LDS_128 = 2 * (128 + 128) * 64 * 2;  // 65536
  constexpr int LDS_64  = 2 * (64 + 128) * 64 * 2;   // 49152

  // ---- 3. CA: merged value + off/attw GEMM (one dispatch) ----
  {
    GemmP pv = mkP(f_ln, w_ca_vw, val_ca, ca_vb, 16384, 1024, 1024, 128);
    GemmP po = mkP(q_ln, w_ca_ow, off_ca, ca_ob, 4096, 768, 1024, 32);
    po.C1 = attw_ca; po.b1 = ca_ab;
    gemm_dual<128, 128><<<1024 + 192, 256, LDS_128, stream>>>(pv, po, 1024);
  }

  // ---- 4. CA sampling + projection ----
  ms_sample_fused<4><<<4096, 256, 0, stream>>>(val_ca, off_ca, attw_ca, samp_ca);
  gemm_v3<64, 128, 0><<<64 * 8, 256, LDS_64, stream>>>(
      mkP(samp_ca, w_ca_pw, attn, ca_pb, 4096, 1024, 1024, 64));

  // ---- 5. SA branch ----
  ln_wave_kernel<<<1024, 256, 0, stream>>>(attn, n1_g, n1_b, attn1);
  {
    GemmP p = mkP(attn1, w_sa_vw, val_sa, sa_vb, 4096, 1216, 1024, 64);
    p.C1 = off_sa; p.b1 = sa_ob; p.C2 = attw_sa; p.b2 = sa_ab;
    gemm_v3<64, 128, 3><<<64 * 10, 256, LDS_64, stream>>>(p);
  }
  ms_sample_fused<1><<<4096, 256, 0, stream>>>(val_sa, off_sa, attw_sa, samp_sa);
  {
    GemmP p = mkP(samp_sa, w_sa_pw, d_out, sa_pb, 4096, 1024, 1024, 64);
    p.src3 = src[3]; p.g1 = gamma1; p.g2 = gamma2; p.attnp = attn;
    gemm_v3<64, 128, 4><<<64 * 8, 256, LDS_64, stream>>>(p);
  }
}

// Round 2
// 355.254 us; speedup vs baseline: 1.0035x; 1.0035x over previous
//
#include <hip/hip_runtime.h>

// ---------------------------------------------------------------------------
// MSCrossAttnBlock on MI355X (gfx950).
// B=4, E=32, LQ=1024, D=1024, NH=16, DH=64, NP=4. All levels are 32x32.
// R6: CA value GEMM ported to 256^2-tile / 512-thread / 4-phase-per-K-tile
//     schedule with counted s_waitcnt vmcnt(8) (never 0 in the loop), one
//     raw s_barrier per phase, setprio(1) around MFMA clusters (T3+T4+T5).
//     Staging runs 5-6 phases ahead of first read; region-level hazard
//     schedule derived from quadrant read-death analysis. off/attw GEMM is
//     its own 192-block 128^2 dispatch on the R5 2-phase path.
//     10 dispatches.
// ---------------------------------------------------------------------------

#define DEV __device__ __forceinline__

typedef float f32x4 __attribute__((ext_vector_type(4)));
typedef __bf16 bf16x8 __attribute__((ext_vector_type(8)));

DEV unsigned short f2bf(float f) {
  union { float f; unsigned u; } a; a.f = f;
  unsigned r = a.u + 0x7fffu + ((a.u >> 16) & 1u);
  return (unsigned short)(r >> 16);
}
DEV float bf2f(unsigned short h) {
  union { unsigned u; float f; } a; a.u = ((unsigned)h) << 16;
  return a.f;
}

// async global -> LDS, 16B per lane; LDS dest = uniform base + lane*16.
DEV void gl_lds16(const unsigned short* g, unsigned short* l) {
  __builtin_amdgcn_global_load_lds(
      (const __attribute__((address_space(1))) void*)g,
      (__attribute__((address_space(3))) void*)l, 16, 0, 0);
}

// ---------------- merged weight fp32 -> bf16 conversion --------------------
struct CvtArgs {
  const float* src[8];
  unsigned short* dst;
  int off4[9];  // prefix sums, float4 units
};

__global__ __launch_bounds__(256) void f2bf_multi(CvtArgs a) {
  int i = blockIdx.x * 256 + threadIdx.x;  // float4 index, exact grid
  int seg = 0;
  #pragma unroll
  for (int s = 1; s < 8; ++s) seg += (i >= a.off4[s]) ? 1 : 0;
  const float4 v = ((const float4*)a.src[seg])[i - a.off4[seg]];
  unsigned short* o = a.dst + (size_t)i * 4;
  o[0] = f2bf(v.x); o[1] = f2bf(v.y); o[2] = f2bf(v.z); o[3] = f2bf(v.w);
}

// ---------------- LayerNorm: one WAVE per row (no barriers, no LDS) --------
DEV void ln_row_wave(const float* __restrict__ xr, const float* __restrict__ g,
                     const float* __restrict__ b,
                     unsigned short* __restrict__ op_row) {
  const int lane = threadIdx.x & 63;
  float4 v[4];
  float s = 0.f, s2 = 0.f;
  #pragma unroll
  for (int j = 0; j < 4; ++j) {
    v[j] = ((const float4*)xr)[lane + 64 * j];
    s  += v[j].x + v[j].y + v[j].z + v[j].w;
    s2 += v[j].x*v[j].x + v[j].y*v[j].y + v[j].z*v[j].z + v[j].w*v[j].w;
  }
  #pragma unroll
  for (int o = 32; o; o >>= 1) { s += __shfl_xor(s, o); s2 += __shfl_xor(s2, o); }
  const float mean = s * (1.f / 1024.f);
  const float rstd = rsqrtf(s2 * (1.f / 1024.f) - mean * mean + 1e-6f);
  #pragma unroll
  for (int j = 0; j < 4; ++j) {
    float4 gg = ((const float4*)g)[lane + 64 * j];
    float4 bb = ((const float4*)b)[lane + 64 * j];
    ushort4 r;
    r.x = f2bf((v[j].x - mean) * rstd * gg.x + bb.x);
    r.y = f2bf((v[j].y - mean) * rstd * gg.y + bb.y);
    r.z = f2bf((v[j].z - mean) * rstd * gg.z + bb.z);
    r.w = f2bf((v[j].w - mean) * rstd * gg.w + bb.w);
    ((ushort4*)op_row)[lane + 64 * j] = r;
  }
}

__global__ __launch_bounds__(256) void ln_wave_kernel(
    const float* __restrict__ x, const float* __restrict__ g,
    const float* __restrict__ b, unsigned short* __restrict__ out) {
  int row = blockIdx.x * 4 + (threadIdx.x >> 6);
  ln_row_wave(x + (size_t)row * 1024, g, b, out + (size_t)row * 1024);
}

// rows 0..16383: feat levels -> f_ln (B,4,1024,1024); rows 16384..20479: q_ln.
__global__ __launch_bounds__(256) void ln5_wave_kernel(
    const float* __restrict__ s0, const float* __restrict__ s1,
    const float* __restrict__ s2, const float* __restrict__ s3,
    const float* __restrict__ fg, const float* __restrict__ fb,
    const float* __restrict__ qg, const float* __restrict__ qb,
    unsigned short* __restrict__ f_out, unsigned short* __restrict__ q_out) {
  int row = blockIdx.x * 4 + (threadIdx.x >> 6);  // 0..20479
  if (row < 16384) {
    int l = row >> 12, inner = row & 4095;
    const float* srcs[4] = {s0, s1, s2, s3};
    int orow = (inner >> 10) * 4096 + l * 1024 + (inner & 1023);
    ln_row_wave(srcs[l] + (size_t)inner * 1024, fg, fb,
                f_out + (size_t)orow * 1024);
  } else {
    int inner = row - 16384;
    ln_row_wave(s3 + (size_t)inner * 1024, qg, qb,
                q_out + (size_t)inner * 1024);
  }
}

// ---------------- shared GEMM param block ----------------------------------
struct GemmP {
  const unsigned short* A; const unsigned short* W;
  void* C; void* C1; void* C2;
  const float* b0; const float* b1; const float* b2;
  const float* src3; const float* g1; const float* g2; const float* attnp;
  int M, N, K, tilesM;
};

// ---------------- 128^2-class bf16 MFMA GEMM (R5 2-phase dbuf) -------------
// EPI: 0=f32, 1=bf16, 2=CA split(off512|attw256), 3=SA split(val1024 bf16|
//      off128 f32|attw64 f32), 4=final combine -> d_out.
template <int BM, int BN, int EPI>
DEV void gemm_body(const GemmP& P, int id, unsigned short* smem) {
  constexpr int WMT = BM / 2, WNT = BN / 2;
  constexpr int MF = WMT / 16, NF = WNT / 16;
  constexpr int PA = BM / 64, PB = BN / 64;    // granule passes per sub-tile
  constexpr int BUF = (BM + BN) * 64;          // elements per LDS buffer
  const int tid = threadIdx.x;
  const int wave = tid >> 6, lane = tid & 63;
  const int wm = (wave & 1) * WMT, wn = (wave >> 1) * WNT;
  const int m0 = (id % P.tilesM) * BM;
  const int n0 = (id / P.tilesM) * BN;
  const int lq = lane >> 4, lm = lane & 15;
  const int r16 = lane >> 2;                    // row within granule
  const int cst = lane & 3;                     // slot within row
  const int csrc = cst ^ ((r16 >> 1) & 3);      // global k-chunk for slot
  const int aslot = lq ^ ((lm >> 1) & 3);       // read slot for chunk lq

  f32x4 acc[MF][NF] = {};
  const int kTiles = P.K >> 6;

  const unsigned short* gA[PA];
  #pragma unroll
  for (int p = 0; p < PA; ++p) {
    int grow = m0 + (wave + 4 * p) * 16 + r16;
    gA[p] = P.A + (size_t)grow * P.K + csrc * 8;
  }
  const unsigned short* gB[PB];
  #pragma unroll
  for (int p = 0; p < PB; ++p) {
    int grow = min(n0 + (wave + 4 * p) * 16 + r16, P.N - 1);
    gB[p] = P.W + (size_t)grow * P.K + csrc * 8;
  }

  auto stage = [&](int b, int t) {
    unsigned short* bA = smem + b * BUF;
    unsigned short* bB = bA + BM * 64;
    const int k0 = t << 6;
    #pragma unroll
    for (int s = 0; s < 2; ++s) {
      #pragma unroll
      for (int p = 0; p < PA; ++p)
        gl_lds16(gA[p] + k0 + s * 32,
                 bA + s * BM * 32 + (wave + 4 * p) * 512);
      #pragma unroll
      for (int p = 0; p < PB; ++p)
        gl_lds16(gB[p] + k0 + s * 32,
                 bB + s * BN * 32 + (wave + 4 * p) * 512);
    }
  };

  stage(0, 0);
  __syncthreads();                 // vmcnt(0) drain: buf0 ready
  int cur = 0;
  #pragma unroll 1
  for (int t = 0; t < kTiles; ++t) {
    if (t + 1 < kTiles) stage(cur ^ 1, t + 1);  // async issue, no wait yet
    const unsigned short* bA = smem + cur * BUF;
    const unsigned short* bB = bA + BM * 64;
    #pragma unroll
    for (int s = 0; s < 2; ++s) {
      bf16x8 af[MF], bfr[NF];
      #pragma unroll
      for (int mi = 0; mi < MF; ++mi)
        af[mi] = *(const bf16x8*)(bA + s * BM * 32 + ((wm >> 4) + mi) * 512 + lm * 32 + aslot * 8);
      #pragma unroll
      for (int ni = 0; ni < NF; ++ni)
        bfr[ni] = *(const bf16x8*)(bB + s * BN * 32 + ((wn >> 4) + ni) * 512 + lm * 32 + aslot * 8);
      #pragma unroll
      for (int mi = 0; mi < MF; ++mi)
        #pragma unroll
        for (int ni = 0; ni < NF; ++ni)
          acc[mi][ni] = __builtin_amdgcn_mfma_f32_16x16x32_bf16(
              af[mi], bfr[ni], acc[mi][ni], 0, 0, 0);
    }
    __syncthreads();   // drains this iter's stage (after MFMA) + barrier
    cur ^= 1;
  }

  #pragma unroll
  for (int mi = 0; mi < MF; ++mi) {
    #pragma unroll
    for (int ni = 0; ni < NF; ++ni) {
      const int col = n0 + wn + ni * 16 + lm;
      #pragma unroll
      for (int r2 = 0; r2 < 4; ++r2) {
        const int row = m0 + wm + mi * 16 + lq * 4 + r2;
        float v = acc[mi][ni][r2];
        if constexpr (EPI == 0) {
          ((float*)P.C)[(size_t)row * 1024 + col] = v + P.b0[col];
        } else if constexpr (EPI == 1) {
          ((unsigned short*)P.C)[(size_t)row * 1024 + col] = f2bf(v + P.b0[col]);
        } else if constexpr (EPI == 2) {
          if (col < 512)
            ((float*)P.C)[(size_t)row * 512 + col] = v + P.b0[col];
          else
            ((float*)P.C1)[(size_t)row * 256 + col - 512] = v + P.b1[col - 512];
        } else if constexpr (EPI == 3) {
          if (col < 1024)
            ((unsigned short*)P.C)[(size_t)row * 1024 + col] = f2bf(v + P.b0[col]);
          else if (col < 1152)
            ((float*)P.C1)[(size_t)row * 128 + col - 1024] = v + P.b1[col - 1024];
          else if (col < 1216)
            ((float*)P.C2)[(size_t)row * 64 + col - 1152] = v + P.b2[col - 1152];
        } else {  // EPI == 4: out = src3 + g1*(attn + g2*(v+b))
          size_t i = (size_t)row * 1024 + col;
          float vv = v + P.b0[col];
          ((float*)P.C)[i] = P.src3[i] + P.g1[col] * (P.attnp[i] + P.g2[col] * vv);
        }
      }
    }
  }
}

template <int BM, int BN, int EPI>
__global__ __launch_bounds__(256) void gemm_v3(GemmP P) {
  extern __shared__ __align__(16) unsigned short smem[];
  gemm_body<BM, BN, EPI>(P, blockIdx.x, smem);
}

// ---------------- 256^2 8-wave 4-phase counted-vmcnt GEMM (CA value) -------
// Tile 256x256, BK=64, 512 threads (2M x 4N waves, each 128x64 output).
// LDS: 2 buffers x (A 32KB + B 32KB) = 128KB static, verified granule layout.
// Per K-tile: 4 phases, each = {vmcnt(8); s_barrier; stage one 16KB region
// 5-6 phases ahead; ds_read frags; setprio(1); 16 MFMA; setprio(0)}.
// Region schedule (quadrant death analysis):
//   p0 computes (qm0,qn0), reads A0+B0 (12 ds_read), stages T(t+1).R3
//   p1 computes (qm0,qn1), reads B1 (4),              stages T(t+1).R1
//   p2 computes (qm1,qn0), reads A1 (8),              stages T(t+2).R0
//   p3 computes (qm1,qn1), reads none,                stages T(t+2).R2
// R0=A rows{0-63,128-191}, R1=A rows{64-127,192-255},
// R2=B rows{wn..wn+31 forall wn}, R3=B rows{wn+32..wn+63}.
// vmcnt(8): every phase's needed region has exactly 8 younger loads (2/phase
// x 4 phases). Epilogue staging clamps src tile to kT-1 (idempotent writes
// into dead regions) so vmcnt counts stay exact; vmcnt(0) once after loop.
__global__ __launch_bounds__(512, 2) void gemm256(GemmP P) {
  __shared__ __align__(16) unsigned short smem[65536];  // 128KB
  const int tid = threadIdx.x;
  const int wave = tid >> 6, lane = tid & 63;
  const int wm = (wave & 1) * 128, wn = (wave >> 1) * 64;
  const int m0 = (blockIdx.x & 63) * 256;   // n-major id: A panel stays on XCD
  const int n0 = (blockIdx.x >> 6) * 256;
  const int lq = lane >> 4, lm = lane & 15;
  const int r16 = lane >> 2, cst = lane & 3;
  const int csrc = cst ^ ((r16 >> 1) & 3);
  const int aslot = lq ^ ((lm >> 1) & 3);
  const int K = P.K;
  const int kT = K >> 6;                     // 16

  // staging granules per wave (one granule per region per s-half)
  const int gA0 = (wave & 3) + ((wave >> 2) << 3);   // R0: {0..3,8..11}
  const int gB2 = ((wave >> 1) << 2) + (wave & 1);   // R2: {0,1,4,5,8,9,12,13}
  const unsigned short* baseA0 =
      P.A + (size_t)(m0 + gA0 * 16 + r16) * K + csrc * 8;
  const unsigned short* baseA1 = baseA0 + (size_t)64 * K;   // R1 = R0 + 4 granules
  const unsigned short* baseB2 =
      P.W + (size_t)(n0 + gB2 * 16 + r16) * K + csrc * 8;
  const unsigned short* baseB3 = baseB2 + (size_t)32 * K;   // R3 = R2 + 2 granules
  const int ldsA0 = gA0 * 512 + lane * 8;
  const int ldsA1 = (gA0 + 4) * 512 + lane * 8;
  const int ldsB2 = 16384 + gB2 * 512 + lane * 8;
  const int ldsB3 = 16384 + (gB2 + 2) * 512 + lane * 8;

  auto stg = [&](const unsigned short* gbase, int ldsOff, int buf, int tsrc) {
    const unsigned short* g = gbase + tsrc * 64;
    unsigned short* l = smem + buf * 32768 + ldsOff;
    gl_lds16(g, l);               // s = 0
    gl_lds16(g + 32, l + 8192);   // s = 1
  };

  const int aBase = (wave & 1) * 8;    // A read granule base
  const int bBase = (wave >> 1) * 4;   // B read granule base
  const int rdI = lm * 32 + aslot * 8;

  auto rdA = [&](int buf, int s, int gi) {
    return *(const bf16x8*)(smem + buf * 32768 + s * 8192 + (aBase + gi) * 512 + rdI);
  };
  auto rdB = [&](int buf, int s, int gi) {
    return *(const bf16x8*)(smem + buf * 32768 + 16384 + s * 8192 + (bBase + gi) * 512 + rdI);
  };

  f32x4 acc[8][4] = {};
  bf16x8 a[2][4], b0[2][2], b1[2][2];

#define VMB8() asm volatile("s_waitcnt vmcnt(8)\ns_barrier" ::: "memory")

  // prologue: T0{R0,R2,R3,R1}, T1{R0,R2} -> 12 loads/wave outstanding
  stg(baseA0, ldsA0, 0, 0);
  stg(baseB2, ldsB2, 0, 0);
  stg(baseB3, ldsB3, 0, 0);
  stg(baseA1, ldsA1, 0, 0);
  stg(baseA0, ldsA0, 1, min(1, kT - 1));
  stg(baseB2, ldsB2, 1, min(1, kT - 1));

  auto iterate = [&](int t, int c) {
    const int nc = c ^ 1;
    const int t1 = min(t + 1, kT - 1);
    const int t2 = min(t + 2, kT - 1);
    // ---- p0: (qm0,qn0) ----
    VMB8();
    stg(baseB3, ldsB3, nc, t1);
    #pragma unroll
    for (int s = 0; s < 2; ++s) {
      #pragma unroll
      for (int i = 0; i < 4; ++i) a[s][i] = rdA(c, s, i);
      #pragma unroll
      for (int i = 0; i < 2; ++i) b0[s][i] = rdB(c, s, i);
    }
    __builtin_amdgcn_s_setprio(1);
    #pragma unroll
    for (int s = 0; s < 2; ++s)
      #pragma unroll
      for (int mi = 0; mi < 4; ++mi)
        #pragma unroll
        for (int ni = 0; ni < 2; ++ni)
          acc[mi][ni] = __builtin_amdgcn_mfma_f32_16x16x32_bf16(
              a[s][mi], b0[s][ni], acc[mi][ni], 0, 0, 0);
    __builtin_amdgcn_s_setprio(0);
    // ---- p1: (qm0,qn1) ----
    VMB8();
    stg(baseA1, ldsA1, nc, t1);
    #pragma unroll
    for (int s = 0; s < 2; ++s)
      #pragma unroll
      for (int i = 0; i < 2; ++i) b1[s][i] = rdB(c, s, 2 + i);
    __builtin_amdgcn_s_setprio(1);
    #pragma unroll
    for (int s = 0; s < 2; ++s)
      #pragma unroll
      for (int mi = 0; mi < 4; ++mi)
        #pragma unroll
        for (int ni = 0; ni < 2; ++ni)
          acc[mi][2 + ni] = __builtin_amdgcn_mfma_f32_16x16x32_bf16(
              a[s][mi], b1[s][ni], acc[mi][2 + ni], 0, 0, 0);
    __builtin_amdgcn_s_setprio(0);
    // ---- p2: (qm1,qn0) ----
    VMB8();
    stg(baseA0, ldsA0, c, t2);
    #pragma unroll
    for (int s = 0; s < 2; ++s)
      #pragma unroll
      for (int i = 0; i < 4; ++i) a[s][i] = rdA(c, s, 4 + i);
    __builtin_amdgcn_s_setprio(1);
    #pragma unroll
    for (int s = 0; s < 2; ++s)
      #pragma unroll
      for (int mi = 0; mi < 4; ++mi)
        #pragma unroll
        for (int ni = 0; ni < 2; ++ni)
          acc[4 + mi][ni] = __builtin_amdgcn_mfma_f32_16x16x32_bf16(
              a[s][mi], b0[s][ni], acc[4 + mi][ni], 0, 0, 0);
    __builtin_amdgcn_s_setprio(0);
    // ---- p3: (qm1,qn1) ----
    VMB8();
    stg(baseB2, ldsB2, c, t2);
    __builtin_amdgcn_s_setprio(1);
    #pragma unroll
    for (int s = 0; s < 2; ++s)
      #pragma unroll
      for (int mi = 0; mi < 4; ++mi)
        #pragma unroll
        for (int ni = 0; ni < 2; ++ni)
          acc[4 + mi][2 + ni] = __builtin_amdgcn_mfma_f32_16x16x32_bf16(
              a[s][mi], b1[s][ni], acc[4 + mi][2 + ni], 0, 0, 0);
    __builtin_amdgcn_s_setprio(0);
  };

  #pragma unroll 1
  for (int t = 0; t < kT; t += 2) {
    iterate(t, 0);
    iterate(t + 1, 1);
  }
  asm volatile("s_waitcnt vmcnt(0)" ::: "memory");
#undef VMB8

  // epilogue: bf16 + bias (EPI==1 semantics), row stride 1024
  #pragma unroll
  for (int mi = 0; mi < 8; ++mi) {
    #pragma unroll
    for (int ni = 0; ni < 4; ++ni) {
      const int col = n0 + wn + ni * 16 + lm;
      #pragma unroll
      for (int r2 = 0; r2 < 4; ++r2) {
        const int row = m0 + wm + mi * 16 + lq * 4 + r2;
        ((unsigned short*)P.C)[(size_t)row * 1024 + col] =
            f2bf(acc[mi][ni][r2] + P.b0[col]);
      }
    }
  }
}

// ---------------- fused softmax + MS-deform bilinear sampling --------------
template <int NLEV>
__global__ __launch_bounds__(256) void ms_sample_fused(
    const unsigned short* __restrict__ value, const float* __restrict__ off,
    const float* __restrict__ logits, unsigned short* __restrict__ out) {
  const int nq = blockIdx.x;               // n*1024 + q
  const int wave = threadIdx.x >> 6, lane = threadIdx.x & 63;
  const int h = (wave << 2) + (lane >> 4);
  const int c = (lane & 15) << 2;          // channel base (0..60)
  const int q = nq & 1023, n = nq >> 10;
  const float* offp = off + ((size_t)nq * 16 + h) * (NLEV * 8);
  const float* lgp  = logits + ((size_t)nq * 16 + h) * (NLEV * 4);

  float lg[NLEV * 4];
  #pragma unroll
  for (int i = 0; i < NLEV; ++i) {
    float4 v = ((const float4*)lgp)[i];
    lg[4*i] = v.x; lg[4*i+1] = v.y; lg[4*i+2] = v.z; lg[4*i+3] = v.w;
  }
  float mx = lg[0];
  #pragma unroll
  for (int i = 1; i < NLEV * 4; ++i) mx = fmaxf(mx, lg[i]);
  float ssum = 0.f;
  #pragma unroll
  for (int i = 0; i < NLEV * 4; ++i) { lg[i] = __expf(lg[i] - mx); ssum += lg[i]; }
  const float inv = 1.f / ssum;

  const float fqx = (float)(q & 31), fqy = (float)(q >> 5);
  float a0 = 0.f, a1 = 0.f, a2 = 0.f, a3 = 0.f;

  #pragma unroll
  for (int l = 0; l < NLEV; ++l) {
    const unsigned short* vl =
        value + ((size_t)(n * NLEV + l) << 20) + h * 64 + c;
    #pragma unroll
    for (int p = 0; p < 4; ++p) {
      float2 o2 = ((const float2*)offp)[l * 4 + p];
      float aw = lg[l * 4 + p] * inv;
      float xx = fqx + o2.x, yy = fqy + o2.y;
      float xf = floorf(xx), yf = floorf(yy);
      float fx = xx - xf, fy = yy - yf;
      int ix = (int)xf, iy = (int)yf;
      int ix1 = ix + 1, iy1 = iy + 1;
      float vx0 = ((unsigned)ix  < 32u) ? 1.f : 0.f;
      float vx1 = ((unsigned)ix1 < 32u) ? 1.f : 0.f;
      float vy0 = ((unsigned)iy  < 32u) ? 1.f : 0.f;
      float vy1 = ((unsigned)iy1 < 32u) ? 1.f : 0.f;
      int cx0 = min(max(ix, 0), 31), cx1 = min(max(ix1, 0), 31);
      int cy0 = min(max(iy, 0), 31), cy1 = min(max(iy1, 0), 31);
      float w00 = (1.f - fx) * (1.f - fy) * vx0 * vy0 * aw;
      float w01 = fx * (1.f - fy) * vx1 * vy0 * aw;
      float w10 = (1.f - fx) * fy * vx0 * vy1 * aw;
      float w11 = fx * fy * vx1 * vy1 * aw;
      ushort4 u00 = *(const ushort4*)(vl + ((size_t)(cy0 * 32 + cx0) << 10));
      ushort4 u01 = *(const ushort4*)(vl + ((size_t)(cy0 * 32 + cx1) << 10));
      ushort4 u10 = *(const ushort4*)(vl + ((size_t)(cy1 * 32 + cx0) << 10));
      ushort4 u11 = *(const ushort4*)(vl + ((size_t)(cy1 * 32 + cx1) << 10));
      a0 += w00 * bf2f(u00.x) + w01 * bf2f(u01.x) + w10 * bf2f(u10.x) + w11 * bf2f(u11.x);
      a1 += w00 * bf2f(u00.y) + w01 * bf2f(u01.y) + w10 * bf2f(u10.y) + w11 * bf2f(u11.y);
      a2 += w00 * bf2f(u00.z) + w01 * bf2f(u01.z) + w10 * bf2f(u10.z) + w11 * bf2f(u11.z);
      a3 += w00 * bf2f(u00.w) + w01 * bf2f(u01.w) + w10 * bf2f(u10.w) + w11 * bf2f(u11.w);
    }
  }
  ushort4 r;
  r.x = f2bf(a0); r.y = f2bf(a1); r.z = f2bf(a2); r.w = f2bf(a3);
  *(ushort4*)(out + ((size_t)nq * 16 + h) * 64 + c) = r;
}

// ---------------------------------------------------------------------------
extern "C" void kernel_launch(void* const* d_in, const int* in_sizes, int n_in,
                              void* d_out, int out_size, void* d_ws,
                              size_t ws_size, hipStream_t stream) {
  (void)in_sizes; (void)n_in; (void)out_size; (void)ws_size;
  const float* src[4] = {(const float*)d_in[0], (const float*)d_in[1],
                         (const float*)d_in[2], (const float*)d_in[3]};
  const float* qn_g = (const float*)d_in[4];
  const float* qn_b = (const float*)d_in[5];
  const float* fn_g = (const float*)d_in[6];
  const float* fn_b = (const float*)d_in[7];
  const float* n1_g = (const float*)d_in[8];
  const float* n1_b = (const float*)d_in[9];
  const float* gamma1 = (const float*)d_in[10];
  const float* gamma2 = (const float*)d_in[11];
  const float* ca_vw = (const float*)d_in[12];
  const float* ca_vb = (const float*)d_in[13];
  const float* ca_ow = (const float*)d_in[14];
  const float* ca_ob = (const float*)d_in[15];
  const float* ca_aw = (const float*)d_in[16];
  const float* ca_ab = (const float*)d_in[17];
  const float* ca_pw = (const float*)d_in[18];
  const float* ca_pb = (const float*)d_in[19];
  const float* sa_vw = (const float*)d_in[20];
  const float* sa_vb = (const float*)d_in[21];
  const float* sa_ow = (const float*)d_in[22];
  const float* sa_ob = (const float*)d_in[23];
  const float* sa_aw = (const float*)d_in[24];
  const float* sa_ab = (const float*)d_in[25];
  const float* sa_pw = (const float*)d_in[26];
  const float* sa_pb = (const float*)d_in[27];

  // ---- workspace layout ----
  char* wsp = (char*)d_ws;
  size_t off = 0;
  auto alloc = [&](size_t bytes) {
    char* r = wsp + off;
    off = (off + bytes + 255) & ~(size_t)255;
    return r;
  };
  const size_t MB = 1024 * 1024;
  unsigned short* w_ca_vw = (unsigned short*)alloc(1024 * 1024 * 2);
  unsigned short* w_ca_ow = (unsigned short*)alloc(512 * 1024 * 2);
  unsigned short* w_ca_aw = (unsigned short*)alloc(256 * 1024 * 2);
  unsigned short* w_ca_pw = (unsigned short*)alloc(1024 * 1024 * 2);
  unsigned short* w_sa_vw = (unsigned short*)alloc(1024 * 1024 * 2);
  unsigned short* w_sa_ow = (unsigned short*)alloc(128 * 1024 * 2);
  unsigned short* w_sa_aw = (unsigned short*)alloc(64 * 1024 * 2);
  unsigned short* w_sa_pw = (unsigned short*)alloc(1024 * 1024 * 2);
  (void)w_ca_aw; (void)w_sa_ow; (void)w_sa_aw;
  char* R1 = alloc(32 * MB);  // f_ln bf16 | attn f32 + attn1 bf16 + samp_sa bf16
  char* R2 = alloc(32 * MB);  // val_ca bf16 | val_sa bf16
  char* R3 = alloc(8 * MB);   // q_ln bf16 | samp_ca bf16
  char* R4 = alloc(8 * MB);   // off_ca f32 | off_sa f32 + attw_sa f32
  char* R5 = alloc(4 * MB);   // attw_ca f32 (raw logits; softmax fused)

  unsigned short* f_ln    = (unsigned short*)R1;
  float*          attn    = (float*)R1;
  unsigned short* attn1   = (unsigned short*)(R1 + 16 * MB);
  unsigned short* samp_sa = (unsigned short*)(R1 + 24 * MB);
  unsigned short* val_ca  = (unsigned short*)R2;
  unsigned short* val_sa  = (unsigned short*)R2;
  unsigned short* q_ln    = (unsigned short*)R3;
  unsigned short* samp_ca = (unsigned short*)R3;
  float*          off_ca  = (float*)R4;
  float*          off_sa  = (float*)R4;
  float*          attw_sa = (float*)(R4 + 4 * MB);
  float*          attw_ca = (float*)R5;

  // ---- 1. merged weight conversion ----
  CvtArgs ca;
  ca.src[0] = ca_vw; ca.src[1] = ca_ow; ca.src[2] = ca_aw; ca.src[3] = ca_pw;
  ca.src[4] = sa_vw; ca.src[5] = sa_ow; ca.src[6] = sa_aw; ca.src[7] = sa_pw;
  ca.dst = w_ca_vw;
  const int sizes4[8] = {262144, 131072, 65536, 262144, 262144, 32768, 16384, 262144};
  ca.off4[0] = 0;
  for (int i = 0; i < 8; ++i) ca.off4[i + 1] = ca.off4[i] + sizes4[i];
  f2bf_multi<<<ca.off4[8] / 256, 256, 0, stream>>>(ca);

  // ---- 2. LayerNorms (feat x4 + query; wave per row) ----
  ln5_wave_kernel<<<5120, 256, 0, stream>>>(src[0], src[1], src[2], src[3],
                                            fn_g, fn_b, qn_g, qn_b, f_ln, q_ln);

  auto mkP = [](const unsigned short* A, const unsigned short* W, void* C,
                const float* b0, int M, int N, int K, int tilesM) {
    GemmP p{}; p.A = A; p.W = W; p.C = C; p.b0 = b0;
    p.M = M; p.N = N; p.K = K; p.tilesM = tilesM;
    return p;
  };

  constexpr int LDS_128 = 2 * (128 + 128) * 64 * 2;  // 65536
  constexpr int LDS_64  = 2 * (64 + 128) * 64 * 2;   // 49152

  // ---- 3. CA: value GEMM (256^2 counted-vmcnt) + off/attw GEMM ----
  gemm256<<<256, 512, 0, stream>>>(
      mkP(f_ln, w_ca_vw, val_ca, ca_vb, 16384, 1024, 1024, 64));
  {
    GemmP po = mkP(q_ln, w_ca_ow, off_ca, ca_ob, 4096, 768, 1024, 32);
    po.C1 = attw_ca; po.b1 = ca_ab;
    gemm_v3<128, 128, 2><<<192, 256, LDS_128, stream>>>(po);
  }

  // ---- 4. CA sampling + projection ----
  ms_sample_fused<4><<<4096, 256, 0, stream>>>(val_ca, off_ca, attw_ca, samp_ca);
  gemm_v3<64, 128, 0><<<64 * 8, 256, LDS_64, stream>>>(
      mkP(samp_ca, w_ca_pw, attn, ca_pb, 4096, 1024, 1024, 64));

  // ---- 5. SA branch ----
  ln_wave_kernel<<<1024, 256, 0, stream>>>(attn, n1_g, n1_b, attn1);
  {
    GemmP p = mkP(attn1, w_sa_vw, val_sa, sa_vb, 4096, 1216, 1024, 64);
    p.C1 = off_sa; p.b1 = sa_ob; p.C2 = attw_sa; p.b2 = sa_ab;
    gemm_v3<64, 128, 3><<<64 * 10, 256, LDS_64, stream>>>(p);
  }
  ms_sample_fused<1><<<4096, 256, 0, stream>>>(val_sa, off_sa, attw_sa, samp_sa);
  {
    GemmP p = mkP(samp_sa, w_sa_pw, d_out, sa_pb, 4096, 1024, 1024, 64);
    p.src3 = src[3]; p.g1 = gamma1; p.g2 = gamma2; p.attnp = attn;
    gemm_v3<64, 128, 4><<<64 * 8, 256, LDS_64, stream>>>(p);
  }
}